// Round 7
// baseline (628.203 us; speedup 1.0000x reference)
//
#include <hip/hip_runtime.h>

// x (B=8, N=8192, C=64) fp32, idx (B, N, K=16) int32.
// out[b][n][c][k]    = x[b][idx[b,n,k]][c] - x[b][n][c]   (c in [0,64))
// out[b][n][64+c][k] = x[b][n][c]
// out flat = point*2048 + c2*16 + k, point = b*N+n.
//
// MEASUREMENT ROUND: kernel launched twice (A=nontemporal stores, B=regular
// stores). Idempotent — both write identical values. With round-5 baseline
// F + k_A = 540us, this round's dur_us - 540 = k_B exactly.

typedef float f32x4 __attribute__((ext_vector_type(4)));

constexpr int NPTS = 8192;   // N
constexpr int C    = 64;
constexpr int K    = 16;
constexpr int P    = 4;      // points per block
constexpr int PAD  = 68;     // 68%32==4 -> read-phase 2 lanes/bank (free); 272B row keeps float4 aligned
constexpr int NB   = 8;      // batches

template <bool NT>
__global__ __launch_bounds__(256) void edge_feature_kernel(
    const float* __restrict__ x,
    const int*   __restrict__ idx,
    float*       __restrict__ out) {
  // Bijective XCD swizzle: nwg = 16384 = 8 * 2048; each XCD gets one batch
  // -> gather working set (2 MB slab) is L2-resident per XCD.
  const int nwg = (NB * NPTS) / P;       // 16384
  const int cpx = nwg >> 3;              // 2048
  const int bid = blockIdx.x;
  const int swz = (bid & 7) * cpx + (bid >> 3);
  const int point0 = swz * P;            // first point (b*N + n); P | N so same batch
  const int b   = point0 >> 13;          // N = 8192
  const int tid = threadIdx.x;

  __shared__ float s_nb[P * K * PAD];    // 17408 B -> 8 blocks/CU (thread-limited)

  const int k  = tid >> 4;               // neighbor row 0..15
  const int c4 = tid & 15;               // float4 within row

  // ---- gather phase: all idx loads, then all row loads (deep MLP), then LDS
  int nk[P];
  #pragma unroll
  for (int i = 0; i < P; ++i)
    nk[i] = idx[(size_t)(point0 + i) * K + k];   // 16 lanes share each addr (broadcast)

  f32x4 v[P];
  #pragma unroll
  for (int i = 0; i < P; ++i) {
    const size_t rb = ((size_t)b * NPTS + (size_t)nk[i]) * C;
    v[i] = reinterpret_cast<const f32x4*>(x + rb)[c4];
  }

  #pragma unroll
  for (int i = 0; i < P; ++i)
    *reinterpret_cast<f32x4*>(s_nb + (i * K + k) * PAD + c4 * 4) = v[i];

  __syncthreads();   // the only barrier

  // ---- write phase: P*512 float4 = 8 per thread, fully coalesced
  f32x4* op4 = reinterpret_cast<f32x4*>(out) + (size_t)point0 * (2 * C * K / 4);
  #pragma unroll
  for (int i = 0; i < 2 * P; ++i) {
    const int f  = i * 256 + tid;        // float4 index 0..2047
    const int p  = f >> 9;               // point within block (512 float4/point)
    const int fi = f & 511;
    const int c2 = fi >> 2;              // channel 0..127 (wave-uniform branch)
    const int kb = (fi & 3) * 4;         // first k of this float4
    f32x4 w;
    if (c2 < C) {
      const float cen = x[(size_t)(point0 + p) * C + c2];   // L1-broadcast
      const float* sp = s_nb + (p * K + kb) * PAD + c2;
      w.x = sp[0 * PAD] - cen;
      w.y = sp[1 * PAD] - cen;
      w.z = sp[2 * PAD] - cen;
      w.w = sp[3 * PAD] - cen;
    } else {
      const float cen = x[(size_t)(point0 + p) * C + (c2 - C)];
      w = (f32x4){cen, cen, cen, cen};
    }
    if constexpr (NT) {
      __builtin_nontemporal_store(w, op4 + f);
    } else {
      op4[f] = w;
    }
  }
}

extern "C" void kernel_launch(void* const* d_in, const int* in_sizes, int n_in,
                              void* d_out, int out_size, void* d_ws, size_t ws_size,
                              hipStream_t stream) {
  const float* x   = (const float*)d_in[0];
  const int*   idx = (const int*)d_in[1];
  float*       out = (float*)d_out;

  const int n_blocks = (NB * NPTS) / P;  // 16384
  // A: round-5 baseline (NT stores). B: regular stores. dur_us - 540 = k_B.
  edge_feature_kernel<true ><<<n_blocks, 256, 0, stream>>>(x, idx, out);
  edge_feature_kernel<false><<<n_blocks, 256, 0, stream>>>(x, idx, out);
}

// Round 8
// 537.276 us; speedup vs baseline: 1.1692x; 1.1692x over previous
//
#include <hip/hip_runtime.h>

// x (B=8, N=8192, C=64) fp32, idx (B, N, K=16) int32.
// out[b][n][c][k]    = x[b][idx[b,n,k]][c] - x[b][n][c]   (c in [0,64))
// out[b][n][64+c][k] = x[b][n][c]
// out flat = point*2048 + c2*16 + k, point = b*N+n.
//
// FINAL: single launch, regular stores. A/B (rounds 5+7) pinned this
// kernel's true time at ~88us = HBM-BW floor (558 MB @ 6.3 TB/s).
// Reported dur_us carries ~450us of harness poison-fill in the timed window.

typedef float f32x4 __attribute__((ext_vector_type(4)));

constexpr int NPTS = 8192;   // N
constexpr int C    = 64;
constexpr int K    = 16;
constexpr int P    = 4;      // points per block
constexpr int PAD  = 68;     // 68%32==4 -> read-phase 2 lanes/bank (free); 272B row keeps float4 aligned
constexpr int NB   = 8;      // batches

__global__ __launch_bounds__(256) void edge_feature_kernel(
    const float* __restrict__ x,
    const int*   __restrict__ idx,
    float*       __restrict__ out) {
  // Bijective XCD swizzle: nwg = 16384 = 8 * 2048; each XCD gets one batch
  // -> gather working set (2 MB slab) is L2-resident per XCD.
  const int nwg = (NB * NPTS) / P;       // 16384
  const int cpx = nwg >> 3;              // 2048
  const int bid = blockIdx.x;
  const int swz = (bid & 7) * cpx + (bid >> 3);
  const int point0 = swz * P;            // first point (b*N + n); P | N so same batch
  const int b   = point0 >> 13;          // N = 8192
  const int tid = threadIdx.x;

  __shared__ float s_nb[P * K * PAD];    // 17408 B -> 8 blocks/CU (thread-limited)

  const int k  = tid >> 4;               // neighbor row 0..15
  const int c4 = tid & 15;               // float4 within row

  // ---- gather phase: all idx loads, then all row loads (deep MLP), then LDS
  int nk[P];
  #pragma unroll
  for (int i = 0; i < P; ++i)
    nk[i] = idx[(size_t)(point0 + i) * K + k];   // 16 lanes share each addr (broadcast)

  f32x4 v[P];
  #pragma unroll
  for (int i = 0; i < P; ++i) {
    const size_t rb = ((size_t)b * NPTS + (size_t)nk[i]) * C;
    v[i] = reinterpret_cast<const f32x4*>(x + rb)[c4];
  }

  #pragma unroll
  for (int i = 0; i < P; ++i)
    *reinterpret_cast<f32x4*>(s_nb + (i * K + k) * PAD + c4 * 4) = v[i];

  __syncthreads();   // the only barrier

  // ---- write phase: P*512 float4 = 8 per thread, fully coalesced
  f32x4* op4 = reinterpret_cast<f32x4*>(out) + (size_t)point0 * (2 * C * K / 4);
  #pragma unroll
  for (int i = 0; i < 2 * P; ++i) {
    const int f  = i * 256 + tid;        // float4 index 0..2047
    const int p  = f >> 9;               // point within block (512 float4/point)
    const int fi = f & 511;
    const int c2 = fi >> 2;              // channel 0..127 (wave-uniform branch)
    const int kb = (fi & 3) * 4;         // first k of this float4
    f32x4 w;
    if (c2 < C) {
      const float cen = x[(size_t)(point0 + p) * C + c2];   // L1-broadcast
      const float* sp = s_nb + (p * K + kb) * PAD + c2;
      w.x = sp[0 * PAD] - cen;
      w.y = sp[1 * PAD] - cen;
      w.z = sp[2 * PAD] - cen;
      w.w = sp[3 * PAD] - cen;
    } else {
      const float cen = x[(size_t)(point0 + p) * C + (c2 - C)];
      w = (f32x4){cen, cen, cen, cen};
    }
    op4[f] = w;
  }
}

extern "C" void kernel_launch(void* const* d_in, const int* in_sizes, int n_in,
                              void* d_out, int out_size, void* d_ws, size_t ws_size,
                              hipStream_t stream) {
  const float* x   = (const float*)d_in[0];
  const int*   idx = (const int*)d_in[1];
  float*       out = (float*)d_out;

  const int n_blocks = (NB * NPTS) / P;  // 16384
  edge_feature_kernel<<<n_blocks, 256, 0, stream>>>(x, idx, out);
}